// Round 1
// baseline (17787.115 us; speedup 1.0000x reference)
//
#include <hip/hip_runtime.h>

// GLIF recurrent network: T=8192 sequential steps, N=1024 neurons.
// Persistent 32-block kernel; block b owns neurons [32b, 32b+32).
// w columns live in VGPRs (128 f32/lane). Cross-block I_add exchange via
// tagged 64-bit agent-scope atomics (tag = step number), double-buffered.

#define T_STEPS 8192
#define N_NEUR  1024
#define NBLK    32
#define COLS    32
#define TPB     256

__global__ void glif_init(unsigned long long* __restrict__ buf) {
    int i = blockIdx.x * blockDim.x + threadIdx.x;
    if (i < N_NEUR) {
        buf[i] = 0ULL;                                // S_0: value 0.0f, tag 0
    } else if (i < 2 * N_NEUR) {
        buf[i] = 0xFFFFFFFF00000000ULL;               // odd buffer: invalid tag
    }
}

__launch_bounds__(TPB, 1)
__global__ void glif_main(const float* __restrict__ x_in,
                          const float* __restrict__ w,
                          const float* __restrict__ E_L_p,
                          const float* __restrict__ tau_m_p,
                          const float* __restrict__ G_p,
                          const float* __restrict__ R_I_p,
                          const float* __restrict__ f_v_p,
                          const float* __restrict__ f_I_p,
                          const float* __restrict__ dths_p,
                          const float* __restrict__ b_s_p,
                          const float* __restrict__ a_v_p,
                          const float* __restrict__ b_v_p,
                          const float* __restrict__ th_inf_p,
                          const float* __restrict__ dV_p,
                          const float* __restrict__ I_A_p,
                          float* __restrict__ out,
                          unsigned long long* __restrict__ buf) {
    const int tid  = threadIdx.x;
    const int wv   = tid >> 6;          // wave 0..3
    const int lane = tid & 63;
    const int half = lane >> 5;         // 0/1
    const int colL = lane & 31;         // local column 0..31
    const int colG = blockIdx.x * COLS + colL;
    const int ibase = wv * 256 + half * 128;   // this lane's i-range start

    __shared__ float ix[N_NEUR];        // staged I_add vector for this step
    __shared__ float red[4 * 32];       // per-wave partial sums

    // ---- one-time: load this lane's 128 w values (column colG, rows ibase..+128)
    float wreg[128];
#pragma unroll
    for (int k = 0; k < 128; ++k) {
        int i = ibase + k;
        float v = w[(size_t)i * N_NEUR + colG];
        wreg[k] = (i == colG) ? 0.0f : v;   // self-recurrence mask (zero diagonal)
    }

    // ---- wave0 lanes 0..31 own the elementwise state for their neuron
    const bool owner = (wv == 0) && (lane < 32);
    float E_L = 0.f, inv_tau = 0.f, Gc = 0.f, R_I = 0.f, f_v = 0.f, f_I = 0.f;
    float dths = 0.f, b_s = 0.f, a_v = 0.f, b_v = 0.f, th_inf = 0.f, dV = 0.f, I_A = 0.f;
    float v = 0.f, th_s = 0.f, th_v = 0.f, I_own = 0.f, xnext = 0.f;
    if (owner) {
        E_L     = E_L_p[colG];
        inv_tau = 1.0f / tau_m_p[colG];
        Gc      = G_p[colG];
        R_I     = R_I_p[colG];
        f_v     = f_v_p[colG];
        f_I     = f_I_p[colG];
        dths    = dths_p[colG];
        b_s     = b_s_p[colG];
        a_v     = a_v_p[colG];
        b_v     = b_v_p[colG];
        th_inf  = th_inf_p[colG];
        dV      = dV_p[colG];
        I_A     = I_A_p[colG];
        v = E_L; th_s = 30.0f; th_v = 1.0f; I_own = 0.0f;
        xnext = x_in[colG];                 // prefetch x for t=0
    }

    float* __restrict__ vs_out = out;
    float* __restrict__ sp_out = out + (size_t)T_STEPS * N_NEUR;

    for (int t = 0; t < T_STEPS; ++t) {
        // ---- phase A: poll tagged I_add (4 u64 per thread) and stage to LDS
        {
            unsigned long long* src = buf + (size_t)(t & 1) * N_NEUR + tid * 4;
            float4 vals;
            unsigned got = 0;
            while (got != 0xFu) {
#pragma unroll
                for (int k = 0; k < 4; ++k) {
                    if (!(got & (1u << k))) {
                        unsigned long long u = __hip_atomic_load(
                            src + k, __ATOMIC_RELAXED, __HIP_MEMORY_SCOPE_AGENT);
                        if ((unsigned)(u >> 32) == (unsigned)t) {
                            (&vals.x)[k] = __uint_as_float((unsigned)(u & 0xFFFFFFFFu));
                            got |= (1u << k);
                        }
                    }
                }
            }
            ((float4*)ix)[tid] = vals;
        }
        // prefetch next step's x (off critical path; used next iteration)
        float xt = xnext;
        if (owner) {
            int tn = (t + 1 < T_STEPS) ? (t + 1) : t;
            xnext = x_in[(size_t)tn * N_NEUR + colG];
        }
        __syncthreads();   // S1: ix ready; also guards red reuse from prev iter

        // ---- phase B: matvec partials from registers
        float acc = 0.0f;
        const float4* ixv = (const float4*)(ix + ibase);
#pragma unroll
        for (int k = 0; k < 32; ++k) {
            float4 q = ixv[k];
            acc = fmaf(wreg[4 * k + 0], q.x, acc);
            acc = fmaf(wreg[4 * k + 1], q.y, acc);
            acc = fmaf(wreg[4 * k + 2], q.z, acc);
            acc = fmaf(wreg[4 * k + 3], q.w, acc);
        }
        acc += __shfl_xor(acc, 32, 64);        // fold the two 128-row halves
        if (lane < 32) red[wv * 32 + lane] = acc;
        __syncthreads();   // S2: red ready

        // ---- phase C: owner lanes do GLIF elementwise + publish
        if (owner) {
            float I = red[colL] + red[32 + colL] + red[64 + colL] + red[96 + colL]
                      + 0.85f * xt;
            float v_next = v + (I * R_I - Gc * (v - E_L)) * inv_tau;
            float thr = th_s + th_v;
            float z = v_next - thr;
            float soft = 1.0f / (1.0f + __expf(-z));   // surrogate spike
            bool  sp = (v_next >= thr);                 // hard spike
            float v_reset = E_L + f_v * (v - E_L) - dV;
            float v_new = sp ? v_reset : v_next;
            th_s = (1.0f - b_s) * th_s + (sp ? dths : 0.0f);
            float d_thv = a_v * (v_new - E_L) - b_v * (th_v - th_inf);
            th_v = th_v + (sp ? 0.0f : d_thv);
            I_own = (1.0f - f_I) * I_own + soft * I_A;
            v = v_new;

            vs_out[(size_t)t * N_NEUR + colG] = v_new;
            sp_out[(size_t)t * N_NEUR + colG] = soft;

            unsigned long long pk =
                ((unsigned long long)(unsigned)(t + 1) << 32) |
                (unsigned long long)__float_as_uint(I_own);
            __hip_atomic_store(buf + (size_t)((t + 1) & 1) * N_NEUR + colG, pk,
                               __ATOMIC_RELAXED, __HIP_MEMORY_SCOPE_AGENT);
        }
    }
}

extern "C" void kernel_launch(void* const* d_in, const int* in_sizes, int n_in,
                              void* d_out, int out_size, void* d_ws, size_t ws_size,
                              hipStream_t stream) {
    const float* x_in   = (const float*)d_in[0];
    const float* w      = (const float*)d_in[1];
    const float* E_L    = (const float*)d_in[2];
    const float* tau_m  = (const float*)d_in[3];
    const float* G      = (const float*)d_in[4];
    const float* R_I    = (const float*)d_in[5];
    const float* f_v    = (const float*)d_in[6];
    const float* f_I    = (const float*)d_in[7];
    const float* dths   = (const float*)d_in[8];
    const float* b_s    = (const float*)d_in[9];
    const float* a_v    = (const float*)d_in[10];
    const float* b_v    = (const float*)d_in[11];
    const float* th_inf = (const float*)d_in[12];
    const float* dV     = (const float*)d_in[13];
    const float* I_A    = (const float*)d_in[14];

    float* out = (float*)d_out;
    unsigned long long* buf = (unsigned long long*)d_ws;  // 2 * 1024 u64 = 16 KB

    glif_init<<<(2 * N_NEUR + TPB - 1) / TPB, TPB, 0, stream>>>(buf);
    glif_main<<<NBLK, TPB, 0, stream>>>(x_in, w, E_L, tau_m, G, R_I, f_v, f_I,
                                        dths, b_s, a_v, b_v, th_inf, dV, I_A,
                                        out, buf);
}